// Round 4
// baseline (715.944 us; speedup 1.0000x reference)
//
#include <hip/hip_runtime.h>
#include <stdint.h>

typedef _Float16 f16;

constexpr int BB   = 4;
constexpr int NN   = 256;
constexpr int CIN  = 256;
constexpr int CHID = 128;
constexpr int HH   = 256;
constexpr int WW   = 256;
constexpr int NPIX = HH * WW;
constexpr int SS   = 256;

// Output layout (fp32 elements, concatenated in return order)
constexpr int OUT_MATCH  = 0;      // [B,N,2] = 2048
constexpr int OUT_VALID  = 2048;   // [B,N]   = 1024
constexpr int OUT_CANDT  = 3072;   // [B,S,3] = 3072
constexpr int OUT_SCORES = 6144;   // [B,S]   = 1024

// A = K_sat * R_sat^T, ub = A*(R_l2w*(Kinv*[u,v,1]*d) + t_init - t_sat)
static __device__ __forceinline__ void compute_geom(
    const float* Kl, const float* Rl, const float* ti,
    const float* Ks, const float* Rs, const float* ts,
    float u, float v, float d, float* A, float* ub)
{
  float a = Kl[0], bq = Kl[1], c = Kl[2];
  float dq = Kl[3], e = Kl[4], f = Kl[5];
  float g = Kl[6], h = Kl[7], i = Kl[8];
  float cof00 =  (e*i - f*h), cof01 = -(dq*i - f*g), cof02 =  (dq*h - e*g);
  float cof10 = -(bq*i - c*h), cof11 =  (a*i - c*g), cof12 = -(a*h - bq*g);
  float cof20 =  (bq*f - c*e), cof21 = -(a*f - c*dq), cof22 =  (a*e - bq*dq);
  float det = a*cof00 + bq*cof01 + c*cof02;
  float inv = 1.0f / det;
  float k00 = cof00*inv, k01 = cof10*inv, k02 = cof20*inv;
  float k10 = cof01*inv, k11 = cof11*inv, k12 = cof21*inv;
  float k20 = cof02*inv, k21 = cof12*inv, k22 = cof22*inv;
  float cx = (k00*u + k01*v + k02) * d;
  float cy = (k10*u + k11*v + k12) * d;
  float cz = (k20*u + k21*v + k22) * d;
  float w0 = Rl[0]*cx + Rl[1]*cy + Rl[2]*cz + ti[0] - ts[0];
  float w1 = Rl[3]*cx + Rl[4]*cy + Rl[5]*cz + ti[1] - ts[1];
  float w2 = Rl[6]*cx + Rl[7]*cy + Rl[8]*cz + ti[2] - ts[2];
  #pragma unroll
  for (int r = 0; r < 3; ++r)
    #pragma unroll
    for (int cJ = 0; cJ < 3; ++cJ)
      A[r*3 + cJ] = Ks[r*3+0]*Rs[cJ*3+0] + Ks[r*3+1]*Rs[cJ*3+1] + Ks[r*3+2]*Rs[cJ*3+2];
  ub[0] = A[0]*w0 + A[1]*w1 + A[2]*w2;
  ub[1] = A[3]*w0 + A[4]*w1 + A[5]*w2;
  ub[2] = A[6]*w0 + A[7]*w1 + A[8]*w2;
}

static __device__ __forceinline__ void proj(const float* A, const float* ub,
                                            float oxr, float oyr,
                                            float& cx, float& cy)
{
  float u0 = ub[0] + oxr*A[0] + oyr*A[1];
  float u1 = ub[1] + oxr*A[3] + oyr*A[4];
  float u2 = ub[2] + oxr*A[6] + oyr*A[7];
  cx = u0 / u2;
  cy = u1 / u2;
}

// ============================ Path A (ws >= ~34MiB) ============================

__global__ __launch_bounds__(256) void kPrep(const float* __restrict__ Wsat,
                                             float* __restrict__ WtG,
                                             float* __restrict__ logits)
{
  int idx = blockIdx.x * 256 + threadIdx.x;      // 0..32767
  int k = idx >> 7, o = idx & 127;
  WtG[idx] = Wsat[o*CIN + k];
  if (idx < BB*SS) logits[idx] = 0.0f;
}

__global__ __launch_bounds__(128) void kNode(const float* __restrict__ feats,
                                             const float* __restrict__ Wn,
                                             const float* __restrict__ bn,
                                             float* __restrict__ nf)
{
  int bnI = blockIdx.x;
  int h = threadIdx.x;
  __shared__ float frow[CIN];
  __shared__ float red[2];
  frow[h]       = feats[(size_t)bnI*CIN + h];
  frow[h + 128] = feats[(size_t)bnI*CIN + h + 128];
  __syncthreads();
  float acc = bn[h];
  #pragma unroll 8
  for (int c = 0; c < CIN; ++c) acc += frow[c] * Wn[c*CHID + h];
  float s = acc * acc;
  #pragma unroll
  for (int off = 32; off; off >>= 1) s += __shfl_down(s, off);
  if ((h & 63) == 0) red[h >> 6] = s;
  __syncthreads();
  float inv = 1.0f / fmaxf(sqrtf(red[0] + red[1]), 1e-12f);
  nf[(size_t)bnI*CHID + h] = acc * inv;
}

// sf = W_sat @ featmap + b_sat, channel-normalized, stored fp16 [B,HW,128].
__global__ __launch_bounds__(256) void kSatH(const float* __restrict__ sat,
                                             const float* __restrict__ WtG,
                                             const float* __restrict__ bsat,
                                             f16* __restrict__ sfn)
{
  const int b = blockIdx.y;
  const int pxbase = blockIdx.x * 128;
  __shared__ float Wt_s[16*128];
  __shared__ float Ft_s[16*128];
  __shared__ float norm2[128];
  const int tid = threadIdx.x;
  const int tx = tid & 15;
  const int ty = tid >> 4;
  if (tid < 128) norm2[tid] = 0.0f;

  float acc[8][8];
  {
    float bsv[8];
    #pragma unroll
    for (int j = 0; j < 8; ++j) {
      int o = (j < 4) ? (tx*4 + j) : (64 + tx*4 + (j - 4));
      bsv[j] = bsat[o];
    }
    #pragma unroll
    for (int i2 = 0; i2 < 8; ++i2)
      #pragma unroll
      for (int j = 0; j < 8; ++j) acc[i2][j] = bsv[j];
  }

  const float* Fb = sat + (size_t)b * CIN * NPIX + pxbase;

  for (int kb = 0; kb < 16; ++kb) {
    {
      const float4* src = (const float4*)(WtG + kb*2048 + tid*8);
      float4 w0 = src[0], w1 = src[1];
      ((float4*)(Wt_s + tid*8))[0] = w0;
      ((float4*)(Wt_s + tid*8))[1] = w1;
    }
    {
      int kk = tid >> 4;
      int p0 = (tid & 15) * 8;
      const float* gsrc = Fb + (size_t)(kb*16 + kk) * NPIX + p0;
      float4 f0 = ((const float4*)gsrc)[0], f1 = ((const float4*)gsrc)[1];
      ((float4*)(Ft_s + kk*128 + p0))[0] = f0;
      ((float4*)(Ft_s + kk*128 + p0))[1] = f1;
    }
    __syncthreads();
    #pragma unroll
    for (int kk = 0; kk < 16; ++kk) {
      float4 wa = *(const float4*)(Wt_s + kk*128 + tx*4);
      float4 wb = *(const float4*)(Wt_s + kk*128 + 64 + tx*4);
      float4 fa = *(const float4*)(Ft_s + kk*128 + ty*4);
      float4 fb = *(const float4*)(Ft_s + kk*128 + 64 + ty*4);
      float fv[8] = {fa.x, fa.y, fa.z, fa.w, fb.x, fb.y, fb.z, fb.w};
      float wv[8] = {wa.x, wa.y, wa.z, wa.w, wb.x, wb.y, wb.z, wb.w};
      #pragma unroll
      for (int i2 = 0; i2 < 8; ++i2)
        #pragma unroll
        for (int j = 0; j < 8; ++j) acc[i2][j] += fv[i2] * wv[j];
    }
    __syncthreads();
  }

  #pragma unroll
  for (int i2 = 0; i2 < 8; ++i2) {
    float s = 0.0f;
    #pragma unroll
    for (int j = 0; j < 8; ++j) s += acc[i2][j] * acc[i2][j];
    int p = (i2 < 4) ? (ty*4 + i2) : (64 + ty*4 + (i2 - 4));
    atomicAdd(&norm2[p], s);
  }
  __syncthreads();
  if (tid < 128) norm2[tid] = 1.0f / fmaxf(sqrtf(norm2[tid]), 1e-12f);
  __syncthreads();

  typedef __attribute__((ext_vector_type(4))) f16 h4;
  #pragma unroll
  for (int i2 = 0; i2 < 8; ++i2) {
    int p = (i2 < 4) ? (ty*4 + i2) : (64 + ty*4 + (i2 - 4));
    float invn = norm2[p];
    size_t rowbase = ((size_t)b * NPIX + pxbase + p) * CHID;
    h4 q0, q1;
    q0.x = (f16)(acc[i2][0]*invn); q0.y = (f16)(acc[i2][1]*invn);
    q0.z = (f16)(acc[i2][2]*invn); q0.w = (f16)(acc[i2][3]*invn);
    q1.x = (f16)(acc[i2][4]*invn); q1.y = (f16)(acc[i2][5]*invn);
    q1.z = (f16)(acc[i2][6]*invn); q1.w = (f16)(acc[i2][7]*invn);
    *(h4*)(sfn + rowbase + tx*4)      = q0;
    *(h4*)(sfn + rowbase + 64 + tx*4) = q1;
  }
}

__global__ __launch_bounds__(256) void kSampleH(
    const f16* __restrict__ sfn, const float* __restrict__ nf,
    const float* __restrict__ node_coords, const float* __restrict__ node_scores,
    const float* __restrict__ node_depths,
    const float* __restrict__ Kl, const float* __restrict__ Rl,
    const float* __restrict__ tinit, const float* __restrict__ Ks,
    const float* __restrict__ Rs, const float* __restrict__ tsat,
    const float* __restrict__ radius, float* __restrict__ logits)
{
  int bnI = blockIdx.x;
  int b = bnI >> 8;
  int tid = threadIdx.x;
  __shared__ float nfs[CHID];
  __shared__ float part[512];
  if (tid < CHID) nfs[tid] = nf[(size_t)bnI*CHID + tid];

  float A[9], ub[3];
  compute_geom(Kl + b*9, Rl + b*9, tinit + b*3, Ks + b*9, Rs + b*9, tsat + b*3,
               node_coords[bnI*2 + 0], node_coords[bnI*2 + 1], node_depths[bnI],
               A, ub);
  float rad = radius[b];
  __syncthreads();

  const int g = tid >> 7;
  const int h = tid & 127;
  const int wv = tid >> 6;
  const int lane = tid & 63;
  const size_t pxb = (size_t)b * NPIX;

  for (int si = 0; si < 128; ++si) {
    int s = si*2 + g;
    int sx = s & 15, sy = s >> 4;
    float oxr = (-1.0f + sx*(2.0f/15.0f)) * rad;
    float oyr = (-1.0f + sy*(2.0f/15.0f)) * rad;
    float cx, cy;
    proj(A, ub, oxr, oyr, cx, cy);
    float px = cx * (256.0f/255.0f) - 0.5f;
    float py = cy * (256.0f/255.0f) - 0.5f;
    float x0f = floorf(px), y0f = floorf(py);
    float wx1 = px - x0f, wy1 = py - y0f;
    float wx0 = 1.0f - wx1, wy0 = 1.0f - wy1;
    int x0 = (int)x0f, y0 = (int)y0f;
    int x1 = x0 + 1, y1 = y0 + 1;
    bool vx0 = (x0 >= 0) && (x0 < WW);
    bool vx1 = (x1 >= 0) && (x1 < WW);
    bool vy0 = (y0 >= 0) && (y0 < HH);
    bool vy1 = (y1 >= 0) && (y1 < HH);
    float val = 0.0f;
    if (vy0) {
      size_t rb = pxb + (size_t)y0 * WW;
      if (vx0) val += wy0*wx0 * (float)sfn[(rb + x0)*CHID + h];
      if (vx1) val += wy0*wx1 * (float)sfn[(rb + x1)*CHID + h];
    }
    if (vy1) {
      size_t rb = pxb + (size_t)y1 * WW;
      if (vx0) val += wy1*wx0 * (float)sfn[(rb + x0)*CHID + h];
      if (vx1) val += wy1*wx1 * (float)sfn[(rb + x1)*CHID + h];
    }
    float p = nfs[h] * val;
    #pragma unroll
    for (int off = 32; off; off >>= 1) p += __shfl_down(p, off);
    if (lane == 0) part[si*4 + wv] = p;
  }
  __syncthreads();
  {
    int s = tid, si = s >> 1, gg = s & 1;
    float sim = part[si*4 + gg*2 + 0] + part[si*4 + gg*2 + 1];
    atomicAdd(&logits[b*SS + s], node_scores[bnI] * sim);
  }
}

// ======================= Path C (zero-workspace fallback) =======================

__global__ __launch_bounds__(256) void kZero(float* stash)
{
  int idx = blockIdx.x * 256 + threadIdx.x;
  if (idx < BB*SS) stash[idx] = 0.0f;
}

// Block per (b,n). On-the-fly sf at 4 corners per sample. Slow but zero-ws.
__global__ __launch_bounds__(256) void kDirectSlow(
    const float* __restrict__ sat, const float* __restrict__ Wsat,
    const float* __restrict__ bsat, const float* __restrict__ feats,
    const float* __restrict__ Wn, const float* __restrict__ bn,
    const float* __restrict__ node_coords, const float* __restrict__ node_scores,
    const float* __restrict__ node_depths,
    const float* __restrict__ Kl, const float* __restrict__ Rl,
    const float* __restrict__ tinit, const float* __restrict__ Ks,
    const float* __restrict__ Rs, const float* __restrict__ tsat,
    const float* __restrict__ radius, float* logitsStash)
{
  __shared__ float frow[CIN];
  __shared__ float nfs[CHID];
  __shared__ float satc[4][CIN];
  __shared__ float sfb[4][256];
  __shared__ float red[8];

  int bnI = blockIdx.x;
  int b = bnI >> 8;
  int tid = threadIdx.x;
  int lane = tid & 63, wv = tid >> 6;

  frow[tid] = feats[(size_t)bnI*CIN + tid];
  __syncthreads();

  {
    float acc = 0.0f;
    if (tid < CHID) {
      acc = bn[tid];
      for (int c = 0; c < CIN; ++c) acc += frow[c] * Wn[c*CHID + tid];
    }
    float s2 = (tid < CHID) ? acc*acc : 0.0f;
    #pragma unroll
    for (int off = 32; off; off >>= 1) s2 += __shfl_down(s2, off);
    if (lane == 0) red[wv] = s2;
    __syncthreads();
    float inv = 1.0f / fmaxf(sqrtf(red[0] + red[1] + red[2] + red[3]), 1e-12f);
    if (tid < CHID) nfs[tid] = acc * inv;
    __syncthreads();
  }

  float A[9], ub[3];
  compute_geom(Kl + b*9, Rl + b*9, tinit + b*3, Ks + b*9, Rs + b*9, tsat + b*3,
               node_coords[bnI*2 + 0], node_coords[bnI*2 + 1], node_depths[bnI],
               A, ub);
  float rad = radius[b];
  float score_n = node_scores[bnI];
  const int h = tid & 127, half = tid >> 7;
  const float* Wrow = Wsat + (size_t)h * CIN + half * 128;

  for (int s = 0; s < SS; ++s) {
    int sx = s & 15, sy = s >> 4;
    float oxr = (-1.0f + sx*(2.0f/15.0f)) * rad;
    float oyr = (-1.0f + sy*(2.0f/15.0f)) * rad;
    float cx, cy;
    proj(A, ub, oxr, oyr, cx, cy);
    float px = cx * (256.0f/255.0f) - 0.5f;
    float py = cy * (256.0f/255.0f) - 0.5f;
    float x0f = floorf(px), y0f = floorf(py);
    float wx1 = px - x0f, wy1 = py - y0f;
    float wx0 = 1.0f - wx1, wy0 = 1.0f - wy1;
    int x0 = (int)x0f, y0 = (int)y0f, x1 = x0 + 1, y1 = y0 + 1;
    int cxs[4] = {x0, x1, x0, x1};
    int cys[4] = {y0, y0, y1, y1};
    float wts[4] = {wy0*wx0, wy0*wx1, wy1*wx0, wy1*wx1};
    #pragma unroll
    for (int j = 0; j < 4; ++j) {
      bool ok = (cxs[j] >= 0) && (cxs[j] < WW) && (cys[j] >= 0) && (cys[j] < HH);
      if (!ok) wts[j] = 0.0f;
      cxs[j] = min(max(cxs[j], 0), WW - 1);
      cys[j] = min(max(cys[j], 0), HH - 1);
    }
    __syncthreads();
    {
      size_t base = (size_t)(b*CIN + tid) * NPIX;
      #pragma unroll
      for (int j = 0; j < 4; ++j)
        satc[j][tid] = sat[base + cys[j]*WW + cxs[j]];
    }
    __syncthreads();
    {
      float a0 = 0.f, a1 = 0.f, a2 = 0.f, a3 = 0.f;
      #pragma unroll 4
      for (int k = 0; k < 128; k += 4) {
        float4 w = *(const float4*)(Wrow + k);
        int kk = half*128 + k;
        a0 += w.x*satc[0][kk] + w.y*satc[0][kk+1] + w.z*satc[0][kk+2] + w.w*satc[0][kk+3];
        a1 += w.x*satc[1][kk] + w.y*satc[1][kk+1] + w.z*satc[1][kk+2] + w.w*satc[1][kk+3];
        a2 += w.x*satc[2][kk] + w.y*satc[2][kk+1] + w.z*satc[2][kk+2] + w.w*satc[2][kk+3];
        a3 += w.x*satc[3][kk] + w.y*satc[3][kk+1] + w.z*satc[3][kk+2] + w.w*satc[3][kk+3];
      }
      sfb[0][tid] = a0; sfb[1][tid] = a1; sfb[2][tid] = a2; sfb[3][tid] = a3;
    }
    __syncthreads();
    float samp = 0.0f;
    #pragma unroll 1
    for (int j = 0; j < 4; ++j) {
      float n2 = 0.0f, nd = 0.0f;
      if (tid < CHID) {
        float sfh = sfb[j][tid] + sfb[j][tid + 128] + bsat[tid];
        n2 = sfh * sfh;
        nd = nfs[tid] * sfh;
      }
      #pragma unroll
      for (int off = 32; off; off >>= 1) {
        n2 += __shfl_down(n2, off);
        nd += __shfl_down(nd, off);
      }
      if (lane == 0) { red[wv*2] = n2; red[wv*2 + 1] = nd; }
      __syncthreads();
      float t1 = red[0] + red[2] + red[4] + red[6];
      float t2 = red[1] + red[3] + red[5] + red[7];
      samp += wts[j] * (t2 / fmaxf(sqrtf(t1), 1e-12f));
      __syncthreads();
    }
    if (tid == 0) atomicAdd(&logitsStash[b*SS + s], score_n * samp);
  }
}

// ================================ epilogue ==================================

// logits may alias the SCORES region of `out` (Path C): thread tid reads
// logits float at index OUT_SCORES+b*SS+tid and later writes scores to the
// exact same float — 1:1 per-thread aliasing, no cross-thread hazard.
__global__ __launch_bounds__(256) void kFinal(
    const float* logits, const float* lscale,
    const float* radius, const float* tinit,
    const float* node_coords, const float* node_depths,
    const float* Kl, const float* Rl,
    const float* Ks, const float* Rs,
    const float* tsat, float* out)
{
  int b = blockIdx.x;
  int tid = threadIdx.x;
  int lane = tid & 63, wv = tid >> 6;
  __shared__ float redm[4], rede[4], av[4];
  __shared__ int ai[4], bestS;

  float scale = expf(lscale[0]);
  float t = logits[b*SS + tid] * scale;

  float m = t;
  #pragma unroll
  for (int off = 32; off; off >>= 1) m = fmaxf(m, __shfl_down(m, off));
  if (lane == 0) redm[wv] = m;
  __syncthreads();
  float M = fmaxf(fmaxf(redm[0], redm[1]), fmaxf(redm[2], redm[3]));

  float e = expf(t - M);
  float se = e;
  #pragma unroll
  for (int off = 32; off; off >>= 1) se += __shfl_down(se, off);
  if (lane == 0) rede[wv] = se;
  __syncthreads();
  float Z = rede[0] + rede[1] + rede[2] + rede[3];

  float vmax = t; int idx = tid;
  #pragma unroll
  for (int off = 32; off; off >>= 1) {
    float ov = __shfl_down(vmax, off);
    int   oi = __shfl_down(idx, off);
    if (ov > vmax || (ov == vmax && oi < idx)) { vmax = ov; idx = oi; }
  }
  if (lane == 0) { av[wv] = vmax; ai[wv] = idx; }
  __syncthreads();
  if (tid == 0) {
    float bv = av[0]; int bi = ai[0];
    #pragma unroll
    for (int w = 1; w < 4; ++w)
      if (av[w] > bv || (av[w] == bv && ai[w] < bi)) { bv = av[w]; bi = ai[w]; }
    bestS = bi;
  }
  __syncthreads();
  int best = bestS;

  out[OUT_SCORES + b*SS + tid] = e / Z;

  float rad = radius[b];
  {
    int sx = tid & 15, sy = tid >> 4;
    float ox = -1.0f + sx*(2.0f/15.0f);
    float oy = -1.0f + sy*(2.0f/15.0f);
    size_t ct = OUT_CANDT + ((size_t)b*SS + tid)*3;
    out[ct + 0] = tinit[b*3 + 0] + ox*rad;
    out[ct + 1] = tinit[b*3 + 1] + oy*rad;
    out[ct + 2] = tinit[b*3 + 2];
  }

  {
    int n = tid;
    int bnI = b*NN + n;
    float A[9], ub[3];
    compute_geom(Kl + b*9, Rl + b*9, tinit + b*3, Ks + b*9, Rs + b*9, tsat + b*3,
                 node_coords[bnI*2 + 0], node_coords[bnI*2 + 1], node_depths[bnI],
                 A, ub);
    int bx = best & 15, by = best >> 4;
    float oxr = (-1.0f + bx*(2.0f/15.0f)) * rad;
    float oyr = (-1.0f + by*(2.0f/15.0f)) * rad;
    float cx, cy;
    proj(A, ub, oxr, oyr, cx, cy);
    out[OUT_MATCH + (size_t)bnI*2 + 0] = cx;
    out[OUT_MATCH + (size_t)bnI*2 + 1] = cy;
    float vl = (cx >= 0.0f && cx < (float)WW && cy >= 0.0f && cy < (float)HH) ? 1.0f : 0.0f;
    out[OUT_VALID + bnI] = vl;
  }
}

extern "C" void kernel_launch(void* const* d_in, const int* in_sizes, int n_in,
                              void* d_out, int out_size, void* d_ws, size_t ws_size,
                              hipStream_t stream)
{
  (void)in_sizes; (void)n_in; (void)out_size;
  const float* node_coords   = (const float*)d_in[0];
  const float* node_scores   = (const float*)d_in[1];
  const float* node_features = (const float*)d_in[2];
  const float* node_depths   = (const float*)d_in[3];
  const float* K_left        = (const float*)d_in[4];
  const float* R_l2w         = (const float*)d_in[5];
  const float* t_init        = (const float*)d_in[6];
  const float* sat           = (const float*)d_in[7];
  const float* K_sat         = (const float*)d_in[8];
  const float* R_sat         = (const float*)d_in[9];
  const float* t_sat         = (const float*)d_in[10];
  const float* radius        = (const float*)d_in[11];
  // d_in[12] = search_steps (int32, 16) — baked in
  const float* W_node        = (const float*)d_in[13];
  const float* b_node        = (const float*)d_in[14];
  const float* W_sat         = (const float*)d_in[15];
  const float* b_sat         = (const float*)d_in[16];
  const float* lscale        = (const float*)d_in[17];

  float* out = (float*)d_out;
  char* ws = (char*)d_ws;

  const size_t sfnB = (size_t)BB * NPIX * CHID * sizeof(f16);   // 32 MiB
  const size_t wtgB = (size_t)CIN * CHID * sizeof(float);       // 128 KiB
  const size_t nfB  = (size_t)BB * NN * CHID * sizeof(float);   // 512 KiB
  const size_t logB = (size_t)BB * SS * sizeof(float);          // 4 KiB
  const size_t needA = sfnB + wtgB + nfB + logB;

  if (ws_size >= needA) {
    f16*   sfn    = (f16*)ws;
    float* WtG    = (float*)(ws + sfnB);
    float* nf     = (float*)(ws + sfnB + wtgB);
    float* logits = (float*)(ws + sfnB + wtgB + nfB);

    kPrep<<<128, 256, 0, stream>>>(W_sat, WtG, logits);
    kNode<<<BB*NN, 128, 0, stream>>>(node_features, W_node, b_node, nf);
    kSatH<<<dim3(NPIX/128, BB), 256, 0, stream>>>(sat, WtG, b_sat, sfn);
    kSampleH<<<BB*NN, 256, 0, stream>>>(sfn, nf, node_coords, node_scores,
        node_depths, K_left, R_l2w, t_init, K_sat, R_sat, t_sat, radius, logits);
    kFinal<<<BB, 256, 0, stream>>>(logits, lscale, radius, t_init, node_coords,
                                   node_depths, K_left, R_l2w, K_sat, R_sat,
                                   t_sat, out);
  } else {
    // zero-workspace fallback: fp32 logits stashed in the SCORES region of out
    float* stash = out + OUT_SCORES;
    kZero<<<4, 256, 0, stream>>>(stash);
    kDirectSlow<<<BB*NN, 256, 0, stream>>>(sat, W_sat, b_sat, node_features,
        W_node, b_node, node_coords, node_scores, node_depths,
        K_left, R_l2w, t_init, K_sat, R_sat, t_sat, radius, stash);
    kFinal<<<BB, 256, 0, stream>>>(stash, lscale, radius, t_init, node_coords,
                                   node_depths, K_left, R_l2w, K_sat, R_sat,
                                   t_sat, out);
  }
}